// Round 9
// baseline (178.631 us; speedup 1.0000x reference)
//
#include <hip/hip_runtime.h>
#include <stdint.h>

typedef unsigned int uint32;
typedef unsigned char u8;
typedef int v4i __attribute__((ext_vector_type(4)));

#define BB 64
#define CC 256
#define OO 256
#define HH 28
#define WW 28
#define HWP 784           // 28*28
#define NWT 589824        // 256*256*9
#define HP 30             // padded spatial (1-px halo each side)
#define XBSTR (HP * HP * 256)   // 230,400 B per padded batch image
#define WTAP (256 * 256)        // 65,536 B per weight tap panel
#define PPIX 272          // LDS bytes per pixel (256 + 16 pad)

// ---------------------------------------------------------------------------
// Kernel 1: cast + transpose + pad activations, LDS-coalesced writes.
// (unchanged from R5 — verified exact)
// ---------------------------------------------------------------------------
__global__ __launch_bounds__(256) void cast_x_kernel(
    const float* __restrict__ x, u8* __restrict__ xi8) {
  __shared__ u8 srow[30 * 260];
  const int hp = blockIdx.x;       // 0..29 padded row
  const int b  = blockIdx.y;       // 0..63
  const int tid = threadIdx.x;
  const int wp = tid & 31;         // 0..31 (30,31 idle on compute)
  const int cq0 = tid >> 5;        // 0..7
  const bool interior = (hp >= 1) && (hp <= 28) && (wp >= 1) && (wp <= 28);
  const float* xp =
      x + (((size_t)b * 256) * 28 + (hp - 1)) * 28 + (wp - 1);  // + c*784
  if (wp < HP) {
#pragma unroll
    for (int it = 0; it < 8; ++it) {
      const int cq = it * 8 + cq0;   // c-quad 0..63
      uint32 v = 0;
      if (interior) {
        const float* p = xp + (size_t)(cq * 4) * HWP;
        uint32 b0 = (p[0] > 0.f) ? 0x01u : 0xFFu;
        uint32 b1 = (p[HWP] > 0.f) ? 0x01u : 0xFFu;
        uint32 b2 = (p[2 * HWP] > 0.f) ? 0x01u : 0xFFu;
        uint32 b3 = (p[3 * HWP] > 0.f) ? 0x01u : 0xFFu;
        v = b0 | (b1 << 8) | (b2 << 16) | (b3 << 24);
      }
      *(uint32*)(&srow[wp * 260 + cq * 4]) = v;
    }
  }
  __syncthreads();
  u8* rowbase = xi8 + (size_t)b * XBSTR + (size_t)hp * 7680;
#pragma unroll
  for (int i = 0; i < 2; ++i) {
    int c = tid + i * 256;           // 16B chunk id, 0..479
    if (c < 480) {
      uint4 v = *(const uint4*)(&srow[(c >> 4) * 260 + (c & 15) * 16]);
      *(uint4*)(rowbase + (size_t)c * 16) = v;
    }
  }
}

// ---------------------------------------------------------------------------
// Kernel 2: weight sign -> i8 tap panels.  wi8[t][o][c] = sign(M + rv.Z).
// (unchanged — verified exact)
// ---------------------------------------------------------------------------
__global__ __launch_bounds__(256) void cast_w_kernel(
    const float* __restrict__ M, const float* __restrict__ Z,
    const float* __restrict__ rv, u8* __restrict__ wi8) {
  __shared__ float sacc[2304];
  const int o = blockIdx.x;
  const int tid = threadIdx.x;
  const size_t base = (size_t)o * 2304;
  float r[8];
#pragma unroll
  for (int k = 0; k < 8; ++k) r[k] = rv[k];
#pragma unroll
  for (int ii = 0; ii < 9; ++ii) {
    int i = tid + ii * 256;  // 2304 = 9*256 exactly
    float s = M[base + i];
#pragma unroll
    for (int k = 0; k < 8; ++k) s += r[k] * Z[(size_t)k * NWT + base + i];
    sacc[i] = s;
  }
  __syncthreads();
  const int c = tid;  // M index i = o*2304 + c*9 + t  (t = kh*3+kw = tap)
#pragma unroll
  for (int t = 0; t < 9; ++t) {
    float s = sacc[c * 9 + t];
    wi8[((size_t)t * 256 + o) * 256 + c] = (s > 0.f) ? (u8)1 : (u8)0xFF;
  }
}

// ---------------------------------------------------------------------------
// Kernel 3 (R8): i8 MFMA implicit-GEMM conv — TLP restructure (32-o waves).
//
// R7 post-mortem: VGPR_Count=128 is ARCH VGPRs only; the 112 accumulators
// sit in AGPRs of the unified file -> true footprint ~240 regs/wave ->
// hard 2-waves/SIMD ceiling (2048/240). Three scheduling variants (rolled,
// full-unroll, explicit ping-pong) all converged to 49-56 µs because there
// is no register headroom to pipeline and 2 lockstep waves can't cover the
// per-k-group load drain. Structure, not schedule, was the limiter.
//
// Fix (m97-GEMM precedent: implicit wave-level TLP at ~12 waves/CU beats
// explicit pipelining): halve the wave tile to 112 px x 32 o -> acc 56,
// ~110-160 regs total. Block = 4 waves x 128 o; grid 7 x 2(o-half) x 64 =
// 896 blocks; __launch_bounds__(256,3) -> 3 blocks/CU (LDS 3x48 KB fits
// 160 KiB) = 3 waves/SIMD. Per-SIMD matrix-pipe subscription ~3x285cy per
// ~700cy group period > 100% -> MFMA-bound target ~15-20 µs.
// Cost accepted: LDS read bytes/MFMA double (512 B -> ~100 B/cy/CU demand,
// at the 85-128 B/cy capacity edge); staging runs 2x per image (FETCH ~2x).
//
// Data layouts, staging, epilogue C/D map byte-identical to R4-R7
// (absmax 0.0 verified every round).
// ---------------------------------------------------------------------------
__global__ __launch_bounds__(256, 3) void conv_mfma_kernel(
    const u8* __restrict__ xi8, const u8* __restrict__ wi8,
    const float* __restrict__ alpha, float* __restrict__ out) {
  __shared__ u8 albs[6 * 30 * PPIX];  // 48,960 B
  const int tid = threadIdx.x;
  const int lane = tid & 63;
  const int wv = tid >> 6;         // wave 0..3
  const int l15 = lane & 15;
  const int lk  = lane >> 4;       // 0..3
  const int pixb = blockIdx.x * 112;
  const int h0   = blockIdx.x * 4;  // first output image row of this block
  const int ob   = blockIdx.y * 128 + wv * 32;  // this wave's first o
  const int b    = blockIdx.z;

  // Stage 6 padded rows (2880 x 16B chunks) global->LDS, 272B pixel stride.
  {
    const u8* gsrc = xi8 + (size_t)b * XBSTR + (size_t)h0 * 7680;
#pragma unroll
    for (int i = 0; i < 12; ++i) {
      int c = tid + i * 256;
      if (c < 2880) {
        uint4 v = *(const uint4*)(gsrc + (size_t)c * 16);
        *(uint4*)(&albs[(c >> 4) * PPIX + (c & 15) * 16]) = v;
      }
    }
  }
  __syncthreads();

  // Per-lane LDS base for the 7 m-tiles at tap (0,0); taps add constants.
  int lb[7];
#pragma unroll
  for (int mt = 0; mt < 7; ++mt) {
    int p = pixb + mt * 16 + l15;        // output pixel of this A-row
    int h = p / 28, w = p - h * 28;
    lb[mt] = ((h - h0) * 30 + w) * PPIX + lk * 16;  // tap(0,0) input px
  }
  const u8* Bb = wi8 + ob * 256;
  const int bvoff = l15 * 256 + lk * 16;

  float aval[2];
#pragma unroll
  for (int ot = 0; ot < 2; ++ot) aval[ot] = alpha[ob + ot * 16 + l15];

  v4i acc[7][2];
#pragma unroll
  for (int mt = 0; mt < 7; ++mt)
#pragma unroll
    for (int ot = 0; ot < 2; ++ot) acc[mt][ot] = v4i{0, 0, 0, 0};

#pragma unroll
  for (int tap = 0; tap < 9; ++tap) {
    const int kh = tap / 3, kw = tap - kh * 3;
    const int toff = (kh * 30 + kw) * PPIX;       // compile-time per tap
    const u8* Bt = Bb + (size_t)tap * WTAP;       // compile-time per tap
#pragma unroll
    for (int ks = 0; ks < 4; ++ks) {
      v4i Bf[2];
#pragma unroll
      for (int ot = 0; ot < 2; ++ot)
        Bf[ot] = *(const v4i*)(Bt + (bvoff + ot * 4096 + ks * 64));
      v4i Af[7];
#pragma unroll
      for (int mt = 0; mt < 7; ++mt)
        Af[mt] = *(const v4i*)(&albs[lb[mt] + toff + ks * 64]);
#pragma unroll
      for (int mt = 0; mt < 7; ++mt)
#pragma unroll
        for (int ot = 0; ot < 2; ++ot)
          acc[mt][ot] = __builtin_amdgcn_mfma_i32_16x16x64_i8(
              Af[mt], Bf[ot], acc[mt][ot], 0, 0, 0);
    }
  }

  // Epilogue: C/D map col=lane&15 (o), row=(lane>>4)*4+reg (pixel). float4
  // stores, 16B aligned (prow % 4 == 0). Verified exact in R4-R7.
#pragma unroll
  for (int mt = 0; mt < 7; ++mt) {
    const int prow = pixb + mt * 16 + lk * 4;
#pragma unroll
    for (int ot = 0; ot < 2; ++ot) {
      float* op = out + ((size_t)b * 256 + (ob + ot * 16 + l15)) * HWP + prow;
      float4 vst;
      vst.x = aval[ot] * (float)acc[mt][ot][0];
      vst.y = aval[ot] * (float)acc[mt][ot][1];
      vst.z = aval[ot] * (float)acc[mt][ot][2];
      vst.w = aval[ot] * (float)acc[mt][ot][3];
      *(float4*)op = vst;
    }
  }
}

// ---------------------------------------------------------------------------
extern "C" void kernel_launch(void* const* d_in, const int* in_sizes, int n_in,
                              void* d_out, int out_size, void* d_ws,
                              size_t ws_size, hipStream_t stream) {
  const float* x     = (const float*)d_in[0];  // (64,256,28,28)
  const float* M     = (const float*)d_in[1];  // (256,256,3,3)
  const float* Z     = (const float*)d_in[2];  // (8,256,256,3,3)
  const float* alpha = (const float*)d_in[3];  // (256,1,1)
  const float* rv    = (const float*)d_in[4];  // (1,8)
  float* out = (float*)d_out;                  // (64,256,28,28)

  u8* xi8 = (u8*)d_ws;                          // 14,745,600 B padded NHWC
  u8* wi8 = (u8*)d_ws + 14745600;               // 589,824 B tap panels

  cast_x_kernel<<<dim3(HP, BB), 256, 0, stream>>>(x, xi8);
  cast_w_kernel<<<dim3(256), 256, 0, stream>>>(M, Z, rv, wi8);
  conv_mfma_kernel<<<dim3(7, 2, BB), 256, 0, stream>>>(xi8, wi8, alpha, out);
}

// Round 10
// 163.103 us; speedup vs baseline: 1.0952x; 1.0952x over previous
//
#include <hip/hip_runtime.h>
#include <stdint.h>

typedef unsigned int uint32;
typedef unsigned char u8;
typedef int v4i __attribute__((ext_vector_type(4)));

#define BB 64
#define CC 256
#define OO 256
#define HH 28
#define WW 28
#define HWP 784           // 28*28
#define NWT 589824        // 256*256*9
#define HP 30             // padded spatial (1-px halo each side)
#define XBSTR (HP * HP * 256)   // 230,400 B per padded batch image
#define WTAP (256 * 256)        // 65,536 B per weight tap panel
#define PPIX 272          // LDS bytes per pixel (256 + 16 pad -> 2-way max)

// ---------------------------------------------------------------------------
// Kernel 1: cast + transpose + pad activations, LDS-coalesced writes.
// (unchanged from R5 — verified exact)
// ---------------------------------------------------------------------------
__global__ __launch_bounds__(256) void cast_x_kernel(
    const float* __restrict__ x, u8* __restrict__ xi8) {
  __shared__ u8 srow[30 * 260];
  const int hp = blockIdx.x;       // 0..29 padded row
  const int b  = blockIdx.y;       // 0..63
  const int tid = threadIdx.x;
  const int wp = tid & 31;         // 0..31 (30,31 idle on compute)
  const int cq0 = tid >> 5;        // 0..7
  const bool interior = (hp >= 1) && (hp <= 28) && (wp >= 1) && (wp <= 28);
  const float* xp =
      x + (((size_t)b * 256) * 28 + (hp - 1)) * 28 + (wp - 1);  // + c*784
  if (wp < HP) {
#pragma unroll
    for (int it = 0; it < 8; ++it) {
      const int cq = it * 8 + cq0;   // c-quad 0..63
      uint32 v = 0;
      if (interior) {
        const float* p = xp + (size_t)(cq * 4) * HWP;
        uint32 b0 = (p[0] > 0.f) ? 0x01u : 0xFFu;
        uint32 b1 = (p[HWP] > 0.f) ? 0x01u : 0xFFu;
        uint32 b2 = (p[2 * HWP] > 0.f) ? 0x01u : 0xFFu;
        uint32 b3 = (p[3 * HWP] > 0.f) ? 0x01u : 0xFFu;
        v = b0 | (b1 << 8) | (b2 << 16) | (b3 << 24);
      }
      *(uint32*)(&srow[wp * 260 + cq * 4]) = v;
    }
  }
  __syncthreads();
  u8* rowbase = xi8 + (size_t)b * XBSTR + (size_t)hp * 7680;
#pragma unroll
  for (int i = 0; i < 2; ++i) {
    int c = tid + i * 256;           // 16B chunk id, 0..479
    if (c < 480) {
      uint4 v = *(const uint4*)(&srow[(c >> 4) * 260 + (c & 15) * 16]);
      *(uint4*)(rowbase + (size_t)c * 16) = v;
    }
  }
}

// ---------------------------------------------------------------------------
// Kernel 2: weight sign -> i8 tap panels.  wi8[t][o][c] = sign(M + rv.Z).
// (unchanged — verified exact)
// ---------------------------------------------------------------------------
__global__ __launch_bounds__(256) void cast_w_kernel(
    const float* __restrict__ M, const float* __restrict__ Z,
    const float* __restrict__ rv, u8* __restrict__ wi8) {
  __shared__ float sacc[2304];
  const int o = blockIdx.x;
  const int tid = threadIdx.x;
  const size_t base = (size_t)o * 2304;
  float r[8];
#pragma unroll
  for (int k = 0; k < 8; ++k) r[k] = rv[k];
#pragma unroll
  for (int ii = 0; ii < 9; ++ii) {
    int i = tid + ii * 256;  // 2304 = 9*256 exactly
    float s = M[base + i];
#pragma unroll
    for (int k = 0; k < 8; ++k) s += r[k] * Z[(size_t)k * NWT + base + i];
    sacc[i] = s;
  }
  __syncthreads();
  const int c = tid;  // M index i = o*2304 + c*9 + t  (t = kh*3+kw = tap)
#pragma unroll
  for (int t = 0; t < 9; ++t) {
    float s = sacc[c * 9 + t];
    wi8[((size_t)t * 256 + o) * 256 + c] = (s > 0.f) ? (u8)1 : (u8)0xFF;
  }
}

// Load k-group g (tap = g/4, ks = g%4): 7 A-fragments from LDS + 4 B-frags
// from L2. Only invoked from a FULLY-UNROLLED loop -> all static indexing.
#define LOADG(g_, AF, BF)                                                      \
  {                                                                            \
    const int tap_ = (g_) >> 2, ks_ = (g_) & 3;                                \
    const int toff_ =                                                          \
        ((tap_ / 3) * 30 + (tap_ % 3)) * PPIX + ks_ * 64;                      \
    _Pragma("unroll") for (int ot = 0; ot < 4; ++ot)                           \
        (BF)[ot] = *(const v4i*)(Bb + ((size_t)tap_ * WTAP) +                  \
                                 (bvoff + ot * 4096 + ks_ * 64));              \
    _Pragma("unroll") for (int mt = 0; mt < 7; ++mt)                           \
        (AF)[mt] = *(const v4i*)(&albs[lb[mt] + toff_]);                       \
  }

#define MFMAG(AF, BF)                                                          \
  {                                                                            \
    _Pragma("unroll") for (int mt = 0; mt < 7; ++mt)                           \
        _Pragma("unroll") for (int ot = 0; ot < 4; ++ot)                       \
            acc[mt][ot] = __builtin_amdgcn_mfma_i32_16x16x64_i8(               \
                (AF)[mt], (BF)[ot], acc[mt][ot], 0, 0, 0);                     \
  }

#define SGB() __builtin_amdgcn_sched_barrier(0)

// ---------------------------------------------------------------------------
// Kernel 3 (R10): i8 MFMA implicit-GEMM conv — sched_barrier-pinned pipeline.
//
// R8/R9 post-mortem: TLP restructure (32-o tiles, occupancy 14->21.6%) made
// conv SLOWER (49.4->61.5 µs) while paying 2x LDS/staging -> wave-count
// latency hiding is NOT the binding constraint. Reverted to the R7 112px x
// 64o structure (best: 49.4 µs).
//
// Standing diagnosis: per k-group exposed stall ~1300 cy vs <=350 cy load
// latency; no pipe saturated. The scheduler sinks prefetch loads back to
// their use sites (legal: no aliasing), converging every source schedule
// to just-in-time issue — VGPR_Count pinned at 128 (4-wave allocator
// target) while the grid can only ever run ~2 waves/SIMD.
//
// Fix: explicit A/B ping-pong + __builtin_amdgcn_sched_barrier(0) fences
// at every LOADG/MFMAG boundary. Loads cannot sink below the fence; MFMAs
// cannot hoist above it -> compiler must emit counted waitcnts with a full
// 28-MFMA (~574 cy) shadow over each group's 11 loads (T4 mechanism).
// Registers: acc 112 AGPR + A-dbuf 56 + B-dbuf 32 + addr ~= 118 arch VGPR
// < 128 -> no spill. launch_bounds(256,2) states the truthful occupancy.
//
// Data layouts, staging, epilogue C/D map byte-identical to R4-R9
// (absmax 0.0 verified every round).
// ---------------------------------------------------------------------------
__global__ __launch_bounds__(256, 2) void conv_mfma_kernel(
    const u8* __restrict__ xi8, const u8* __restrict__ wi8,
    const float* __restrict__ alpha, float* __restrict__ out) {
  __shared__ u8 albs[6 * 30 * PPIX];  // 48,960 B
  const int tid = threadIdx.x;
  const int lane = tid & 63;
  const int wv = tid >> 6;         // wave 0..3 -> o-quarter
  const int l15 = lane & 15;
  const int lk  = lane >> 4;       // 0..3
  const int pixb = blockIdx.x * 112;
  const int h0   = blockIdx.x * 4;  // first output image row of this block
  const int b    = blockIdx.y;

  // Stage 6 padded rows (2880 x 16B chunks) global->LDS, 272B pixel stride.
  {
    const u8* gsrc = xi8 + (size_t)b * XBSTR + (size_t)h0 * 7680;
#pragma unroll
    for (int i = 0; i < 12; ++i) {
      int c = tid + i * 256;
      if (c < 2880) {
        uint4 v = *(const uint4*)(gsrc + (size_t)c * 16);
        *(uint4*)(&albs[(c >> 4) * PPIX + (c & 15) * 16]) = v;
      }
    }
  }
  __syncthreads();

  // Per-lane LDS base for the 7 m-tiles at tap (0,0); taps add constants.
  int lb[7];
#pragma unroll
  for (int mt = 0; mt < 7; ++mt) {
    int p = pixb + mt * 16 + l15;        // output pixel of this A-row
    int h = p / 28, w = p - h * 28;
    lb[mt] = ((h - h0) * 30 + w) * PPIX + lk * 16;  // tap(0,0) input px
  }
  const u8* Bb = wi8 + wv * (64 * 256);
  const int bvoff = l15 * 256 + lk * 16;

  float aval[4];
#pragma unroll
  for (int ot = 0; ot < 4; ++ot) aval[ot] = alpha[wv * 64 + ot * 16 + l15];

  v4i acc[7][4];
#pragma unroll
  for (int mt = 0; mt < 7; ++mt)
#pragma unroll
    for (int ot = 0; ot < 4; ++ot) acc[mt][ot] = v4i{0, 0, 0, 0};

  // 36 k-groups (9 taps x 4 ks), depth-1 ping-pong, fence-pinned schedule.
  v4i A0[7], B0[4], A1[7], B1[4];
  LOADG(0, A0, B0);
#pragma unroll
  for (int g = 0; g < 36; g += 2) {
    LOADG(g + 1, A1, B1);          // prefetch odd group
    SGB();                         // loads may not sink below this point
    MFMAG(A0, B0);                 // ~574 cy shadow over the prefetch
    SGB();
    if (g + 2 < 36) LOADG(g + 2, A0, B0);  // prefetch next even group
    SGB();
    MFMAG(A1, B1);
    SGB();
  }

  // Epilogue: C/D map col=lane&15 (o), row=(lane>>4)*4+reg (pixel). float4
  // stores, 16B aligned (prow % 4 == 0). Verified exact in R4-R9.
#pragma unroll
  for (int mt = 0; mt < 7; ++mt) {
    const int prow = pixb + mt * 16 + lk * 4;
#pragma unroll
    for (int ot = 0; ot < 4; ++ot) {
      float* op = out +
          ((size_t)b * 256 + (wv * 64 + ot * 16 + l15)) * HWP + prow;
      float4 vst;
      vst.x = aval[ot] * (float)acc[mt][ot][0];
      vst.y = aval[ot] * (float)acc[mt][ot][1];
      vst.z = aval[ot] * (float)acc[mt][ot][2];
      vst.w = aval[ot] * (float)acc[mt][ot][3];
      *(float4*)op = vst;
    }
  }
}

// ---------------------------------------------------------------------------
extern "C" void kernel_launch(void* const* d_in, const int* in_sizes, int n_in,
                              void* d_out, int out_size, void* d_ws,
                              size_t ws_size, hipStream_t stream) {
  const float* x     = (const float*)d_in[0];  // (64,256,28,28)
  const float* M     = (const float*)d_in[1];  // (256,256,3,3)
  const float* Z     = (const float*)d_in[2];  // (8,256,256,3,3)
  const float* alpha = (const float*)d_in[3];  // (256,1,1)
  const float* rv    = (const float*)d_in[4];  // (1,8)
  float* out = (float*)d_out;                  // (64,256,28,28)

  u8* xi8 = (u8*)d_ws;                          // 14,745,600 B padded NHWC
  u8* wi8 = (u8*)d_ws + 14745600;               // 589,824 B tap panels

  cast_x_kernel<<<dim3(HP, BB), 256, 0, stream>>>(x, xi8);
  cast_w_kernel<<<dim3(256), 256, 0, stream>>>(M, Z, rv, wi8);
  conv_mfma_kernel<<<dim3(7, BB), 256, 0, stream>>>(xi8, wi8, alpha, out);
}